// Round 2
// baseline (761.936 us; speedup 1.0000x reference)
//
#include <hip/hip_runtime.h>

#define D4 512        // 2048 floats = 512 float4 per row
#define K_EDGES 32    // sorted edges per wave-chunk (one 32-lane meta load)

// ---------- sort machinery: counting sort by (rel, dst_half, src) ----------
// Bucket layout (64-aligned regions, ndp/npp multiples of 64):
//   g0 [0,ndp)        rel0 dhalf0   g1 [ndp,2ndp)       rel0 dhalf1
//   g2 [2ndp,3ndp)    rel1 dhalf0   g3 [3ndp,4ndp)      rel1 dhalf1
//   g4 [4ndp,4ndp+npp) rel2 dhalf0  g5 [...,4ndp+2npp)  rel2 dhalf1
// dhalf0 buckets bump-allocate upward from 0, dhalf1 downward from E, so the
// relation segment is [dhalf0 groups..][..dhalf1 groups] — temporal dst
// locality (smaller L3 working set per sub-phase) with zero extra passes.

__global__ void zero_ints(int* __restrict__ p, int n) {
    int i = blockIdx.x * blockDim.x + threadIdx.x;
    if (i < n) p[i] = 0;
}

__global__ void hist3(const int* __restrict__ s0, const int* __restrict__ d0_,
                      const int* __restrict__ s1, const int* __restrict__ d1_,
                      const int* __restrict__ s2, const int* __restrict__ d2_,
                      int E, int* __restrict__ cnt,
                      int ndp, int npp, int hd, int hp) {
    int i = blockIdx.x * blockDim.x + threadIdx.x;
    const int total = 3 * E;
    for (; i < total; i += gridDim.x * blockDim.x) {
        int b;
        if (i < E)           { b = (d0_[i] < hd ? 0 : ndp) + s0[i]; }
        else if (i < 2 * E)  { int k = i - E;     b = 2 * ndp + (d1_[k] < hp ? 0 : ndp) + s1[k]; }
        else                 { int k = i - 2 * E; b = 4 * ndp + (d2_[k] < hp ? 0 : npp) + s2[k]; }
        atomicAdd(&cnt[b], 1);
    }
}

// bump-allocate contiguous region per bucket; wave shfl-scan + 1 atomic/wave.
// even groups: upward from 0; odd groups: downward from E.
__global__ void alloc3(const int* __restrict__ cnt, int* __restrict__ base,
                       int* __restrict__ cursors, int ndp, int npp, int E, int CBp) {
    int i = blockIdx.x * blockDim.x + threadIdx.x;
    if (i >= CBp) return;                  // whole waves only (regions 64-aligned)
    const int lane = threadIdx.x & 63;
    int g;                                  // wave-uniform group id
    if (i < 2 * ndp)      g = (i < ndp) ? 0 : 1;
    else if (i < 4 * ndp) g = (i < 3 * ndp) ? 2 : 3;
    else                  g = (i < 4 * ndp + npp) ? 4 : 5;
    int c = cnt[i];
    int x = c;                              // inclusive scan across the wave
#pragma unroll
    for (int d = 1; d < 64; d <<= 1) {
        int y = __shfl_up(x, d, 64);
        if (lane >= d) x += y;
    }
    int tot = __shfl(x, 63);
    int wb = 0;
    if (lane == 63) wb = atomicAdd(&cursors[g], tot);
    wb = __shfl(wb, 63);
    // exclusive offset within this group's allocation stream
    int ex = wb + x - c;
    base[i] = (g & 1) ? (E - ex - c) : ex;  // odd groups fill from the top
}

__global__ void scatter3(const int* __restrict__ s0, const int* __restrict__ d0_,
                         const int* __restrict__ s1, const int* __restrict__ d1_,
                         const int* __restrict__ s2, const int* __restrict__ d2_,
                         int E, int* __restrict__ base, int ndp, int npp,
                         int hd, int hp,
                         int* __restrict__ sorted, int* __restrict__ sd) {
    int i = blockIdx.x * blockDim.x + threadIdx.x;
    const int total = 3 * E;
    for (; i < total; i += gridDim.x * blockDim.x) {
        if (i < E) {
            int s = s0[i], d = d0_[i];
            int b = (d < hd ? 0 : ndp) + s;
            int p = atomicAdd(&base[b], 1);
            sorted[p] = i; sd[p] = (s << 16) | d;
        } else if (i < 2 * E) {
            int k = i - E; int s = s1[k], d = d1_[k];
            int b = 2 * ndp + (d < hp ? 0 : ndp) + s;
            int p = atomicAdd(&base[b], 1);
            sorted[E + p] = k; sd[E + p] = (s << 16) | d;
        } else {
            int k = i - 2 * E; int s = s2[k], d = d2_[k];
            int b = 4 * ndp + (d < hp ? 0 : npp) + s;
            int p = atomicAdd(&base[b], 1);
            sorted[2 * E + p] = k; sd[2 * E + p] = (s << 16) | d;
        }
    }
}

// ---------- scoring over (rel, dst-half, src)-grouped edges ----------
// waves_per_eu(4,4) pins the allocator at a 128-VGPR budget so hr+tA+tB
// (96 regs) actually live in registers (round-1: allocator targeted 8 w/EU,
// spilled to scratch, WRITE_SIZE 44MB). rel row is L1-resident — reloaded at
// src switches instead of cached (saves 32 VGPRs). 4 accumulators shorten the
// serial FMA chain 32 -> 8+merge.
__global__ __launch_bounds__(256)
__attribute__((amdgpu_waves_per_eu(4, 4)))
void score_sorted(
    const float4* __restrict__ xdrug, const float4* __restrict__ xprot,
    const float4* __restrict__ rddi,  const float4* __restrict__ rdpi,
    const int* __restrict__ sorted, const int* __restrict__ sd,
    int* __restrict__ queue, float* __restrict__ out, int E)
{
    const int lane = threadIdx.x & 63;
    const int wpb = blockDim.x >> 6;
    const int wid = blockIdx.x * wpb + (threadIdx.x >> 6);
    const int nw = gridDim.x * wpb;
    const int cpr = (E + K_EDGES - 1) / K_EDGES;
    const int total_chunks = 3 * cpr;

    int c = wid;
    while (c < total_chunks) {
        const int r = (c >= 2 * cpr) ? 2 : (c >= cpr) ? 1 : 0;
        const int ci = c - r * cpr;
        const int e_lo = ci * K_EDGES;
        const int n = min(K_EDGES, E - e_lo);

        const float4 *xs, *xd, *rel;
        if (r == 0)      { xs = xdrug; xd = xdrug; rel = rddi; }
        else if (r == 1) { xs = xdrug; xd = xprot; rel = rdpi; }
        else             { xs = xprot; xd = xprot; rel = rdpi; }
        const int* sl  = sorted + (size_t)r * E + e_lo;
        const int* sdl = sd     + (size_t)r * E + e_lo;
        float* o = out + (size_t)r * E;

        int eL = 0, sdL = 0;
        if (lane < n) { eL = sl[lane]; sdL = sdl[lane]; }

        float4 hr[8], tA[8], tB[8];
        int cur = -1;

        {   // prologue: tail row for edge 0
            int sd0 = __shfl(sdL, 0);
            const float4* tp = xd + (size_t)(sd0 & 0xffff) * D4;
#pragma unroll
            for (int j = 0; j < 8; ++j) tA[j] = tp[j * 64 + lane];
        }

        for (int i = 0; i < n; i += 2) {
            if (i + 1 < n) {    // prefetch edge i+1 tail into tB
                int sdn = __shfl(sdL, i + 1);
                const float4* tq = xd + (size_t)(sdn & 0xffff) * D4;
#pragma unroll
                for (int j = 0; j < 8; ++j) tB[j] = tq[j * 64 + lane];
            }
            {   // compute edge i from tA
                int sdi = __shfl(sdL, i);
                int s = sdi >> 16;
                if (s != cur) {               // wave-uniform branch
                    cur = s;
                    const float4* hp = xs + (size_t)s * D4;
#pragma unroll
                    for (int j = 0; j < 8; ++j) {
                        float4 h = hp[j * 64 + lane], rv = rel[j * 64 + lane];
                        hr[j].x = h.x * rv.x; hr[j].y = h.y * rv.y;
                        hr[j].z = h.z * rv.z; hr[j].w = h.w * rv.w;
                    }
                }
                float a0 = 0.f, a1 = 0.f, a2 = 0.f, a3 = 0.f;
#pragma unroll
                for (int j = 0; j < 8; ++j) {
                    a0 = fmaf(hr[j].x, tA[j].x, a0);
                    a1 = fmaf(hr[j].y, tA[j].y, a1);
                    a2 = fmaf(hr[j].z, tA[j].z, a2);
                    a3 = fmaf(hr[j].w, tA[j].w, a3);
                }
                float acc = (a0 + a1) + (a2 + a3);
#pragma unroll
                for (int off = 32; off; off >>= 1) acc += __shfl_down(acc, off, 64);
                int e = __shfl(eL, i);
                if (lane == 0) o[e] = fminf(fmaxf(acc, 0.f), 1.f);
            }
            if (i + 1 >= n) break;
            if (i + 2 < n) {    // prefetch edge i+2 tail into tA
                int sdn = __shfl(sdL, i + 2);
                const float4* tq = xd + (size_t)(sdn & 0xffff) * D4;
#pragma unroll
                for (int j = 0; j < 8; ++j) tA[j] = tq[j * 64 + lane];
            }
            {   // compute edge i+1 from tB
                int sdi = __shfl(sdL, i + 1);
                int s = sdi >> 16;
                if (s != cur) {
                    cur = s;
                    const float4* hp = xs + (size_t)s * D4;
#pragma unroll
                    for (int j = 0; j < 8; ++j) {
                        float4 h = hp[j * 64 + lane], rv = rel[j * 64 + lane];
                        hr[j].x = h.x * rv.x; hr[j].y = h.y * rv.y;
                        hr[j].z = h.z * rv.z; hr[j].w = h.w * rv.w;
                    }
                }
                float a0 = 0.f, a1 = 0.f, a2 = 0.f, a3 = 0.f;
#pragma unroll
                for (int j = 0; j < 8; ++j) {
                    a0 = fmaf(hr[j].x, tB[j].x, a0);
                    a1 = fmaf(hr[j].y, tB[j].y, a1);
                    a2 = fmaf(hr[j].z, tB[j].z, a2);
                    a3 = fmaf(hr[j].w, tB[j].w, a3);
                }
                float acc = (a0 + a1) + (a2 + a3);
#pragma unroll
                for (int off = 32; off; off >>= 1) acc += __shfl_down(acc, off, 64);
                int e = __shfl(eL, i + 1);
                if (lane == 0) o[e] = fminf(fmaxf(acc, 0.f), 1.f);
            }
        }

        // dynamic work queue: perfect load balance
        int nc = 0;
        if (lane == 0) nc = atomicAdd(queue, 1);
        c = nw + __shfl(nc, 0);
    }
}

// ---------- fallback (direct kernel) if ws too small ----------
__global__ __launch_bounds__(256) void edge_score_all(
    const float4* __restrict__ xdrug, const float4* __restrict__ xprot,
    const float4* __restrict__ rddi,  const float4* __restrict__ rdpi,
    const int* __restrict__ ddi_src, const int* __restrict__ ddi_dst,
    const int* __restrict__ dpi_src, const int* __restrict__ dpi_dst,
    const int* __restrict__ ppi_src, const int* __restrict__ ppi_dst,
    float* __restrict__ out, int E)
{
    __shared__ float4 srel[2][D4];
    for (int i = threadIdx.x; i < D4; i += blockDim.x) {
        srel[0][i] = rddi[i];
        srel[1][i] = rdpi[i];
    }
    __syncthreads();
    const int lane = threadIdx.x & 63;
    const int wpb = blockDim.x >> 6;
    int wid = blockIdx.x * wpb + (threadIdx.x >> 6);
    const int nw = gridDim.x * wpb;
    const int total = 3 * E;
    for (int e = wid; e < total; e += nw) {
        const float4 *hp, *tp;
        int sel;
        if (e < E)          { hp = xdrug + (size_t)ddi_src[e] * D4; tp = xdrug + (size_t)ddi_dst[e] * D4; sel = 0; }
        else if (e < 2 * E) { int k = e - E;     hp = xdrug + (size_t)dpi_src[k] * D4; tp = xprot + (size_t)dpi_dst[k] * D4; sel = 1; }
        else                { int k = e - 2 * E; hp = xprot + (size_t)ppi_src[k] * D4; tp = xprot + (size_t)ppi_dst[k] * D4; sel = 1; }
        float acc = 0.f;
#pragma unroll
        for (int j = 0; j < 8; ++j) {
            const int idx = j * 64 + lane;
            float4 h = hp[idx], t = tp[idx], rr = srel[sel][idx];
            acc = fmaf(h.x * rr.x, t.x, acc);
            acc = fmaf(h.y * rr.y, t.y, acc);
            acc = fmaf(h.z * rr.z, t.z, acc);
            acc = fmaf(h.w * rr.w, t.w, acc);
        }
#pragma unroll
        for (int off = 32; off; off >>= 1) acc += __shfl_down(acc, off, 64);
        if (lane == 0) out[e] = fminf(fmaxf(acc, 0.f), 1.f);
    }
}

extern "C" void kernel_launch(void* const* d_in, const int* in_sizes, int n_in,
                              void* d_out, int out_size, void* d_ws, size_t ws_size,
                              hipStream_t stream) {
    const float* x_drug    = (const float*)d_in[0];
    const float* x_protein = (const float*)d_in[1];
    const float* rel_ddi   = (const float*)d_in[2];
    const float* rel_dpi   = (const float*)d_in[3];
    const int* ddi_src = (const int*)d_in[4];
    const int* ddi_dst = (const int*)d_in[5];
    const int* dpi_src = (const int*)d_in[6];
    const int* dpi_dst = (const int*)d_in[7];
    const int* ppi_src = (const int*)d_in[8];
    const int* ppi_dst = (const int*)d_in[9];

    const int D  = in_sizes[2];              // 2048
    const int nd = in_sizes[0] / D;          // N_DRUG
    const int np = in_sizes[1] / D;          // N_PROT
    const int E  = in_sizes[4];              // edges per relation
    float* out = (float*)d_out;

    const int ndp = ((nd + 63) / 64) * 64;   // 64-aligned region sizes
    const int npp = ((np + 63) / 64) * 64;
    const int CBp = 4 * ndp + 2 * npp;       // buckets: (rel, dst_half, src)
    const int hd  = nd >> 1;                 // drug dst-half threshold
    const int hp  = np >> 1;                 // protein dst-half threshold

    const size_t need = (size_t)(2 * CBp + 16 + 6 * E) * sizeof(int);

    if (ws_size < need) {                    // fallback: direct kernel
        edge_score_all<<<2048, 256, 0, stream>>>(
            (const float4*)x_drug, (const float4*)x_protein,
            (const float4*)rel_ddi, (const float4*)rel_dpi,
            ddi_src, ddi_dst, dpi_src, dpi_dst, ppi_src, ppi_dst, out, E);
        return;
    }

    int* cnt    = (int*)d_ws;                // CBp ints
    int* aux    = cnt + CBp;                 // 16 ints: cursors[0..5], queue at [8]
    int* base   = aux + 16;                  // CBp ints (becomes scatter cursor)
    int* sorted = base + CBp;                // 3E ints  (edge ids, grouped order)
    int* sd     = sorted + 3 * E;            // 3E ints  ((src<<16)|dst, same order)

    zero_ints<<<(CBp + 16 + 255) / 256, 256, 0, stream>>>(cnt, CBp + 16);
    hist3<<<2048, 256, 0, stream>>>(ddi_src, ddi_dst, dpi_src, dpi_dst,
                                    ppi_src, ppi_dst, E, cnt, ndp, npp, hd, hp);
    alloc3<<<(CBp + 255) / 256, 256, 0, stream>>>(cnt, base, aux, ndp, npp, E, CBp);
    scatter3<<<2048, 256, 0, stream>>>(ddi_src, ddi_dst, dpi_src, dpi_dst,
                                       ppi_src, ppi_dst, E, base, ndp, npp,
                                       hd, hp, sorted, sd);

    score_sorted<<<1024, 256, 0, stream>>>(
        (const float4*)x_drug, (const float4*)x_protein,
        (const float4*)rel_ddi, (const float4*)rel_dpi,
        sorted, sd, aux + 8, out, E);
}

// Round 4
// 624.154 us; speedup vs baseline: 1.2208x; 1.2208x over previous
//
#include <hip/hip_runtime.h>
#include <hip/hip_fp16.h>

#define D4 512        // 2048 floats = 512 float4 per row (f32 rows)
#define T4 256        // 2048 halves = 256 float4 per row (fp16 rows)
#define K_EDGES 16    // sorted edges per wave-chunk

// ================= conversion: fp16 tail mirrors with rel folded ==========
// drug16[i] = fp16(rel_ddi * x_drug[i])    (drug-as-tail only occurs in ddi)
// prot16[i] = fp16(rel_dpi * x_protein[i]) (protein-as-tail: dpi AND ppi use rel_dpi)
__global__ __launch_bounds__(256) void cvt16(
    const float4* __restrict__ xd, const float4* __restrict__ xp,
    const float4* __restrict__ rddi, const float4* __restrict__ rdpi,
    __half* __restrict__ drug16, __half* __restrict__ prot16,
    int nd4, int np4)   // float4 counts: nd*512, np*512
{
    int i = blockIdx.x * blockDim.x + threadIdx.x;
    const int total = nd4 + np4;
    for (; i < total; i += gridDim.x * blockDim.x) {
        float4 v, r; __half* o; int idx;
        if (i < nd4) { v = xd[i];          r = rddi[i & 511]; o = drug16; idx = i; }
        else { int k = i - nd4; v = xp[k]; r = rdpi[k & 511]; o = prot16; idx = k; }
        __half2 h01 = __floats2half2_rn(v.x * r.x, v.y * r.y);
        __half2 h23 = __floats2half2_rn(v.z * r.z, v.w * r.w);
        uint2 pk = make_uint2(*(const unsigned*)&h01, *(const unsigned*)&h23);
        ((uint2*)o)[idx] = pk;            // 4 halves per source float4
    }
}

// ================= counting sort by (rel, src) — round-0 scheme ===========
__global__ void zero_ints(int* __restrict__ p, int n) {
    int i = blockIdx.x * blockDim.x + threadIdx.x;
    if (i < n) p[i] = 0;
}

// buckets: [0,ndp) rel0 | [ndp,2ndp) rel1 | [2ndp,2ndp+npp) rel2
__global__ void hist3(const int* __restrict__ s0, const int* __restrict__ s1,
                      const int* __restrict__ s2, int E,
                      int* __restrict__ cnt, int ndp) {
    int i = blockIdx.x * blockDim.x + threadIdx.x;
    const int total = 3 * E;
    for (; i < total; i += gridDim.x * blockDim.x) {
        if (i < E)           atomicAdd(&cnt[s0[i]], 1);
        else if (i < 2 * E)  atomicAdd(&cnt[ndp + s1[i - E]], 1);
        else                 atomicAdd(&cnt[2 * ndp + s2[i - 2 * E]], 1);
    }
}

// bump-alloc contiguous region per bucket: wave shfl-scan + 1 atomic/wave.
// Region order arbitrary within a relation — grouping is all we need.
__global__ void alloc3(const int* __restrict__ cnt, int* __restrict__ base,
                       int* __restrict__ cursors, int ndp, int CB) {
    int i = blockIdx.x * blockDim.x + threadIdx.x;
    if (i >= CB) return;                   // whole waves only (ndp/npp 64-aligned)
    const int lane = threadIdx.x & 63;
    const int g = (i < ndp) ? 0 : (i < 2 * ndp) ? 1 : 2;   // wave-uniform
    int c = cnt[i];
    int x = c;
#pragma unroll
    for (int d = 1; d < 64; d <<= 1) {
        int y = __shfl_up(x, d, 64);
        if (lane >= d) x += y;
    }
    int tot = __shfl(x, 63);
    int wb = 0;
    if (lane == 63) wb = atomicAdd(&cursors[g], tot);
    wb = __shfl(wb, 63);
    base[i] = wb + x - c;                  // exclusive offset within relation
}

__global__ void scatter3(const int* __restrict__ s0, const int* __restrict__ d0_,
                         const int* __restrict__ s1, const int* __restrict__ d1_,
                         const int* __restrict__ s2, const int* __restrict__ d2_,
                         int E, int* __restrict__ base, int ndp,
                         int* __restrict__ sorted, int* __restrict__ sd) {
    int i = blockIdx.x * blockDim.x + threadIdx.x;
    const int total = 3 * E;
    for (; i < total; i += gridDim.x * blockDim.x) {
        if (i < E) {
            int s = s0[i], d = d0_[i];
            int p = atomicAdd(&base[s], 1);
            sorted[p] = i; sd[p] = (s << 16) | d;
        } else if (i < 2 * E) {
            int k = i - E; int s = s1[k], d = d1_[k];
            int p = atomicAdd(&base[ndp + s], 1);
            sorted[E + p] = k; sd[E + p] = (s << 16) | d;
        } else {
            int k = i - 2 * E; int s = s2[k], d = d2_[k];
            int p = atomicAdd(&base[2 * ndp + s], 1);
            sorted[2 * E + p] = k; sd[2 * E + p] = (s << 16) | d;
        }
    }
}

// ================= fp16 scoring (filter pass) =============================
// Head rows f32, register-cached per src-run (rel already folded into tails,
// so hr = plain head row). Tail rows stream as fp16 (4KB/edge, half of f32).
// Head load pattern matches tail granules: lane owns flat values
// [8*(g*64+lane), +8) — two adjacent head float4s, one fp16 tail float4.
// Edges with pre-clip fp16 score inside (-1.5, 2.5) (~68 sigma of the fp16
// quantization error, std ~0.022) are queued for exact f32 refinement; all
// other edges saturate to 0/1 identically to the f32 reference.
__global__ __launch_bounds__(256) void score16(
    const float4* __restrict__ xdrug, const float4* __restrict__ xprot,
    const float4* __restrict__ drug16, const float4* __restrict__ prot16,
    const int* __restrict__ sorted, const int* __restrict__ sd,
    int* __restrict__ refine, int* __restrict__ rcnt,
    float* __restrict__ out, int E)
{
    const int lane = threadIdx.x & 63;
    const int wpb = blockDim.x >> 6;
    const int wid = blockIdx.x * wpb + (threadIdx.x >> 6);
    const int nw = gridDim.x * wpb;
    const int cpr = (E + K_EDGES - 1) / K_EDGES;
    const int total_chunks = 3 * cpr;

    for (int c = wid; c < total_chunks; c += nw) {
        const int r = (c >= 2 * cpr) ? 2 : (c >= cpr) ? 1 : 0;
        const int ci = c - r * cpr;
        const int e_lo = ci * K_EDGES;
        const int n = min(K_EDGES, E - e_lo);

        const float4* xs = (r < 2) ? xdrug : xprot;    // head (f32)
        const float4* xt = (r == 0) ? drug16 : prot16; // tail (fp16, rel folded)
        const int* sl  = sorted + (size_t)r * E + e_lo;
        const int* sdl = sd     + (size_t)r * E + e_lo;
        float* o = out + (size_t)r * E;

        int eL = 0, sdL = 0;               // chunk metadata in lanes, shfl out
        if (lane < n) { eL = sl[lane]; sdL = sdl[lane]; }

        float4 hr[8];
        int cur = -1;

        for (int i = 0; i < n; ++i) {
            const int sdi = __shfl(sdL, i);   // convergent: whole wave
            const int e   = __shfl(eL, i);    // convergent: whole wave
            const int s = sdi >> 16;
            if (s != cur) {                // wave-uniform branch
                cur = s;
                const float4* hp = xs + (size_t)s * D4;
#pragma unroll
                for (int g = 0; g < 4; ++g) {
                    hr[2 * g]     = hp[2 * (g * 64 + lane)];
                    hr[2 * g + 1] = hp[2 * (g * 64 + lane) + 1];
                }
            }
            const float4* tq = xt + (size_t)(sdi & 0xffff) * T4;
            float a0 = 0.f, a1 = 0.f, a2 = 0.f, a3 = 0.f;
#pragma unroll
            for (int g = 0; g < 4; ++g) {
                float4 tv = tq[g * 64 + lane];
                const __half2* t2 = (const __half2*)&tv;
                float2 f0 = __half22float2(t2[0]);
                float2 f1 = __half22float2(t2[1]);
                float2 f2 = __half22float2(t2[2]);
                float2 f3 = __half22float2(t2[3]);
                a0 = fmaf(hr[2 * g].x, f0.x, a0);
                a1 = fmaf(hr[2 * g].y, f0.y, a1);
                a2 = fmaf(hr[2 * g].z, f1.x, a2);
                a3 = fmaf(hr[2 * g].w, f1.y, a3);
                a0 = fmaf(hr[2 * g + 1].x, f2.x, a0);
                a1 = fmaf(hr[2 * g + 1].y, f2.y, a1);
                a2 = fmaf(hr[2 * g + 1].z, f3.x, a2);
                a3 = fmaf(hr[2 * g + 1].w, f3.y, a3);
            }
            float acc = (a0 + a1) + (a2 + a3);
#pragma unroll
            for (int off = 32; off; off >>= 1) acc += __shfl_down(acc, off, 64);
            if (lane == 0) {
                o[e] = fminf(fmaxf(acc, 0.f), 1.f);
                if (acc > -1.5f && acc < 2.5f) {
                    int p = atomicAdd(rcnt, 1);
                    refine[p] = (r << 20) | e;   // e < 2^17, r < 4
                }
            }
        }
    }
}

// ================= f32 refinement of borderline edges =====================
__global__ __launch_bounds__(256) void refine_f32(
    const float4* __restrict__ xdrug, const float4* __restrict__ xprot,
    const float4* __restrict__ rddi,  const float4* __restrict__ rdpi,
    const int* __restrict__ ddi_src, const int* __restrict__ ddi_dst,
    const int* __restrict__ dpi_src, const int* __restrict__ dpi_dst,
    const int* __restrict__ ppi_src, const int* __restrict__ ppi_dst,
    const int* __restrict__ refine, const int* __restrict__ rcnt,
    float* __restrict__ out, int E)
{
    const int lane = threadIdx.x & 63;
    const int wpb = blockDim.x >> 6;
    const int wid = blockIdx.x * wpb + (threadIdx.x >> 6);
    const int nw = gridDim.x * wpb;
    const int count = rcnt[0];
    for (int k = wid; k < count; k += nw) {
        const int pe = refine[k];
        const int r = pe >> 20, e = pe & 0xFFFFF;
        const float4 *hp, *tp, *rel;
        if (r == 0)      { hp = xdrug + (size_t)ddi_src[e] * D4; tp = xdrug + (size_t)ddi_dst[e] * D4; rel = rddi; }
        else if (r == 1) { hp = xdrug + (size_t)dpi_src[e] * D4; tp = xprot + (size_t)dpi_dst[e] * D4; rel = rdpi; }
        else             { hp = xprot + (size_t)ppi_src[e] * D4; tp = xprot + (size_t)ppi_dst[e] * D4; rel = rdpi; }
        float a0 = 0.f, a1 = 0.f, a2 = 0.f, a3 = 0.f;
#pragma unroll
        for (int j = 0; j < 8; ++j) {
            const int idx = j * 64 + lane;
            float4 h = hp[idx], t = tp[idx], rv = rel[idx];
            a0 = fmaf(h.x * rv.x, t.x, a0);
            a1 = fmaf(h.y * rv.y, t.y, a1);
            a2 = fmaf(h.z * rv.z, t.z, a2);
            a3 = fmaf(h.w * rv.w, t.w, a3);
        }
        float acc = (a0 + a1) + (a2 + a3);
#pragma unroll
        for (int off = 32; off; off >>= 1) acc += __shfl_down(acc, off, 64);
        if (lane == 0) out[(size_t)r * E + e] = fminf(fmaxf(acc, 0.f), 1.f);
    }
}

// ================= mid-tier: f32 sorted path (round-0 proven) =============
__global__ __launch_bounds__(256) void score_f32(
    const float4* __restrict__ xdrug, const float4* __restrict__ xprot,
    const float4* __restrict__ rddi,  const float4* __restrict__ rdpi,
    const int* __restrict__ sorted, const int* __restrict__ sd,
    float* __restrict__ out, int E)
{
    const int lane = threadIdx.x & 63;
    const int wpb = blockDim.x >> 6;
    const int wid = blockIdx.x * wpb + (threadIdx.x >> 6);
    const int nw = gridDim.x * wpb;
    const int cpr = (E + K_EDGES - 1) / K_EDGES;
    const int total_chunks = 3 * cpr;

    for (int c = wid; c < total_chunks; c += nw) {
        const int r = (c >= 2 * cpr) ? 2 : (c >= cpr) ? 1 : 0;
        const int ci = c - r * cpr;
        const int e_lo = ci * K_EDGES;
        const int n = min(K_EDGES, E - e_lo);

        const float4 *xs, *xd, *rel;
        if (r == 0)      { xs = xdrug; xd = xdrug; rel = rddi; }
        else if (r == 1) { xs = xdrug; xd = xprot; rel = rdpi; }
        else             { xs = xprot; xd = xprot; rel = rdpi; }
        const int* sl  = sorted + (size_t)r * E + e_lo;
        const int* sdl = sd     + (size_t)r * E + e_lo;
        float* o = out + (size_t)r * E;

        float4 hr[8];
        int cur = -1;
        for (int i = 0; i < n; ++i) {
            const int e = sl[i];
            const int sdi = sdl[i];
            const int s = sdi >> 16;
            if (s != cur) {
                cur = s;
                const float4* hp = xs + (size_t)s * D4;
#pragma unroll
                for (int j = 0; j < 8; ++j) {
                    float4 h = hp[j * 64 + lane], rv = rel[j * 64 + lane];
                    hr[j].x = h.x * rv.x; hr[j].y = h.y * rv.y;
                    hr[j].z = h.z * rv.z; hr[j].w = h.w * rv.w;
                }
            }
            const float4* tp = xd + (size_t)(sdi & 0xffff) * D4;
            float acc = 0.f;
#pragma unroll
            for (int j = 0; j < 8; ++j) {
                float4 t = tp[j * 64 + lane];
                acc = fmaf(hr[j].x, t.x, acc);
                acc = fmaf(hr[j].y, t.y, acc);
                acc = fmaf(hr[j].z, t.z, acc);
                acc = fmaf(hr[j].w, t.w, acc);
            }
#pragma unroll
            for (int off = 32; off; off >>= 1) acc += __shfl_down(acc, off, 64);
            if (lane == 0) o[e] = fminf(fmaxf(acc, 0.f), 1.f);
        }
    }
}

// ================= last-resort direct kernel ==============================
__global__ __launch_bounds__(256) void edge_score_all(
    const float4* __restrict__ xdrug, const float4* __restrict__ xprot,
    const float4* __restrict__ rddi,  const float4* __restrict__ rdpi,
    const int* __restrict__ ddi_src, const int* __restrict__ ddi_dst,
    const int* __restrict__ dpi_src, const int* __restrict__ dpi_dst,
    const int* __restrict__ ppi_src, const int* __restrict__ ppi_dst,
    float* __restrict__ out, int E)
{
    __shared__ float4 srel[2][D4];
    for (int i = threadIdx.x; i < D4; i += blockDim.x) {
        srel[0][i] = rddi[i];
        srel[1][i] = rdpi[i];
    }
    __syncthreads();
    const int lane = threadIdx.x & 63;
    const int wpb = blockDim.x >> 6;
    int wid = blockIdx.x * wpb + (threadIdx.x >> 6);
    const int nw = gridDim.x * wpb;
    const int total = 3 * E;
    for (int e = wid; e < total; e += nw) {
        const float4 *hp, *tp;
        int sel;
        if (e < E)          { hp = xdrug + (size_t)ddi_src[e] * D4; tp = xdrug + (size_t)ddi_dst[e] * D4; sel = 0; }
        else if (e < 2 * E) { int k = e - E;     hp = xdrug + (size_t)dpi_src[k] * D4; tp = xprot + (size_t)dpi_dst[k] * D4; sel = 1; }
        else                { int k = e - 2 * E; hp = xprot + (size_t)ppi_src[k] * D4; tp = xprot + (size_t)ppi_dst[k] * D4; sel = 1; }
        float acc = 0.f;
#pragma unroll
        for (int j = 0; j < 8; ++j) {
            const int idx = j * 64 + lane;
            float4 h = hp[idx], t = tp[idx], rr = srel[sel][idx];
            acc = fmaf(h.x * rr.x, t.x, acc);
            acc = fmaf(h.y * rr.y, t.y, acc);
            acc = fmaf(h.z * rr.z, t.z, acc);
            acc = fmaf(h.w * rr.w, t.w, acc);
        }
#pragma unroll
        for (int off = 32; off; off >>= 1) acc += __shfl_down(acc, off, 64);
        if (lane == 0) out[e] = fminf(fmaxf(acc, 0.f), 1.f);
    }
}

extern "C" void kernel_launch(void* const* d_in, const int* in_sizes, int n_in,
                              void* d_out, int out_size, void* d_ws, size_t ws_size,
                              hipStream_t stream) {
    const float* x_drug    = (const float*)d_in[0];
    const float* x_protein = (const float*)d_in[1];
    const float* rel_ddi   = (const float*)d_in[2];
    const float* rel_dpi   = (const float*)d_in[3];
    const int* ddi_src = (const int*)d_in[4];
    const int* ddi_dst = (const int*)d_in[5];
    const int* dpi_src = (const int*)d_in[6];
    const int* dpi_dst = (const int*)d_in[7];
    const int* ppi_src = (const int*)d_in[8];
    const int* ppi_dst = (const int*)d_in[9];

    const int D  = in_sizes[2];              // 2048
    const int nd = in_sizes[0] / D;          // N_DRUG
    const int np = in_sizes[1] / D;          // N_PROT
    const int E  = in_sizes[4];              // edges per relation
    float* out = (float*)d_out;

    const int ndp = ((nd + 63) / 64) * 64;   // 64-aligned
    const int npp = ((np + 63) / 64) * 64;
    const int CB  = 2 * ndp + npp;           // buckets: (rel, src)

    const size_t b_d16 = (size_t)nd * D * 2; // fp16 mirror sizes (16B-aligned)
    const size_t b_p16 = (size_t)np * D * 2;
    const size_t ints_sort = (size_t)(2 * CB + 16 + 6 * E) * sizeof(int);
    const size_t need_sort = ints_sort;
    const size_t need_full = b_d16 + b_p16 + ints_sort + (size_t)3 * E * sizeof(int);

    if (ws_size < need_sort) {               // last resort: direct kernel
        edge_score_all<<<2048, 256, 0, stream>>>(
            (const float4*)x_drug, (const float4*)x_protein,
            (const float4*)rel_ddi, (const float4*)rel_dpi,
            ddi_src, ddi_dst, dpi_src, dpi_dst, ppi_src, ppi_dst, out, E);
        return;
    }

    const bool full = (ws_size >= need_full);
    char* wp = (char*)d_ws;
    __half* drug16 = nullptr; __half* prot16 = nullptr;
    if (full) {
        drug16 = (__half*)wp;  wp += b_d16;  // 16B-aligned (D*2 = 4096B rows)
        prot16 = (__half*)wp;  wp += b_p16;
    }
    int* cnt    = (int*)wp;                  // CB
    int* aux    = cnt + CB;                  // 16: cursors[0..2], rcnt at [8]
    int* base   = aux + 16;                  // CB
    int* sorted = base + CB;                 // 3E (edge ids, src-grouped)
    int* sd     = sorted + 3 * E;            // 3E ((src<<16)|dst)
    int* refine = sd + 3 * E;                // 3E worst case (full path only)

    if (full)
        cvt16<<<2048, 256, 0, stream>>>(
            (const float4*)x_drug, (const float4*)x_protein,
            (const float4*)rel_ddi, (const float4*)rel_dpi,
            drug16, prot16, nd * (D / 4), np * (D / 4));

    zero_ints<<<(CB + 16 + 255) / 256, 256, 0, stream>>>(cnt, CB + 16);
    hist3<<<1024, 256, 0, stream>>>(ddi_src, dpi_src, ppi_src, E, cnt, ndp);
    alloc3<<<(CB + 255) / 256, 256, 0, stream>>>(cnt, base, aux, ndp, CB);
    scatter3<<<1024, 256, 0, stream>>>(ddi_src, ddi_dst, dpi_src, dpi_dst,
                                       ppi_src, ppi_dst, E, base, ndp, sorted, sd);

    if (full) {
        score16<<<2048, 256, 0, stream>>>(
            (const float4*)x_drug, (const float4*)x_protein,
            (const float4*)drug16, (const float4*)prot16,
            sorted, sd, refine, aux + 8, out, E);
        refine_f32<<<1024, 256, 0, stream>>>(
            (const float4*)x_drug, (const float4*)x_protein,
            (const float4*)rel_ddi, (const float4*)rel_dpi,
            ddi_src, ddi_dst, dpi_src, dpi_dst, ppi_src, ppi_dst,
            refine, aux + 8, out, E);
    } else {
        score_f32<<<2048, 256, 0, stream>>>(
            (const float4*)x_drug, (const float4*)x_protein,
            (const float4*)rel_ddi, (const float4*)rel_dpi,
            sorted, sd, out, E);
    }
}

// Round 5
// 579.078 us; speedup vs baseline: 1.3158x; 1.0778x over previous
//
#include <hip/hip_runtime.h>
#include <hip/hip_fp16.h>

#define D4 512        // 2048 floats = 512 float4 per row (f32 rows)
#define T4 256        // 2048 halves = 256 float4 per row (fp16 rows)
#define K_EDGES 16    // sorted edges per wave-chunk

// ================= conversion: plain fp16 mirrors (no rel fold) ===========
// Single mirror per matrix, used for BOTH heads and tails -> steady-state
// working set 120 MB (nd+np rows fp16), fully L3-resident. rel is applied
// in-registers at head-run switches (f32 rel row is L1-hot).
__global__ __launch_bounds__(256) void cvt16(
    const float4* __restrict__ xd, const float4* __restrict__ xp,
    __half* __restrict__ drug16, __half* __restrict__ prot16,
    int nd4, int np4)   // float4 counts: nd*512, np*512
{
    int i = blockIdx.x * blockDim.x + threadIdx.x;
    const int total = nd4 + np4;
    for (; i < total; i += gridDim.x * blockDim.x) {
        float4 v; __half* o; int idx;
        if (i < nd4) { v = xd[i]; o = drug16; idx = i; }
        else         { v = xp[i - nd4]; o = prot16; idx = i - nd4; }
        __half2 h01 = __floats2half2_rn(v.x, v.y);
        __half2 h23 = __floats2half2_rn(v.z, v.w);
        uint2 pk = make_uint2(*(const unsigned*)&h01, *(const unsigned*)&h23);
        ((uint2*)o)[idx] = pk;            // 4 halves per source float4
    }
}

// ================= counting sort by (rel, src) ============================
__global__ void zero_ints(int* __restrict__ p, int n) {
    int i = blockIdx.x * blockDim.x + threadIdx.x;
    if (i < n) p[i] = 0;
}

// buckets: [0,ndp) rel0 | [ndp,2ndp) rel1 | [2ndp,2ndp+npp) rel2
__global__ void hist3(const int* __restrict__ s0, const int* __restrict__ s1,
                      const int* __restrict__ s2, int E,
                      int* __restrict__ cnt, int ndp) {
    int i = blockIdx.x * blockDim.x + threadIdx.x;
    const int total = 3 * E;
    for (; i < total; i += gridDim.x * blockDim.x) {
        if (i < E)           atomicAdd(&cnt[s0[i]], 1);
        else if (i < 2 * E)  atomicAdd(&cnt[ndp + s1[i - E]], 1);
        else                 atomicAdd(&cnt[2 * ndp + s2[i - 2 * E]], 1);
    }
}

// bump-alloc contiguous region per bucket: wave shfl-scan + 1 atomic/wave.
__global__ void alloc3(const int* __restrict__ cnt, int* __restrict__ base,
                       int* __restrict__ cursors, int ndp, int CB) {
    int i = blockIdx.x * blockDim.x + threadIdx.x;
    if (i >= CB) return;                   // whole waves only (ndp/npp 64-aligned)
    const int lane = threadIdx.x & 63;
    const int g = (i < ndp) ? 0 : (i < 2 * ndp) ? 1 : 2;   // wave-uniform
    int c = cnt[i];
    int x = c;
#pragma unroll
    for (int d = 1; d < 64; d <<= 1) {
        int y = __shfl_up(x, d, 64);
        if (lane >= d) x += y;
    }
    int tot = __shfl(x, 63);
    int wb = 0;
    if (lane == 63) wb = atomicAdd(&cursors[g], tot);
    wb = __shfl(wb, 63);
    base[i] = wb + x - c;                  // exclusive offset within relation
}

__global__ void scatter3(const int* __restrict__ s0, const int* __restrict__ d0_,
                         const int* __restrict__ s1, const int* __restrict__ d1_,
                         const int* __restrict__ s2, const int* __restrict__ d2_,
                         int E, int* __restrict__ base, int ndp,
                         int* __restrict__ sorted, int* __restrict__ sd) {
    int i = blockIdx.x * blockDim.x + threadIdx.x;
    const int total = 3 * E;
    for (; i < total; i += gridDim.x * blockDim.x) {
        if (i < E) {
            int s = s0[i], d = d0_[i];
            int p = atomicAdd(&base[s], 1);
            sorted[p] = i; sd[p] = (s << 16) | d;
        } else if (i < 2 * E) {
            int k = i - E; int s = s1[k], d = d1_[k];
            int p = atomicAdd(&base[ndp + s], 1);
            sorted[E + p] = k; sd[E + p] = (s << 16) | d;
        } else {
            int k = i - 2 * E; int s = s2[k], d = d2_[k];
            int p = atomicAdd(&base[2 * ndp + s], 1);
            sorted[2 * E + p] = k; sd[2 * E + p] = (s << 16) | d;
        }
    }
}

// ================= fp16 scoring (filter pass) =============================
// Head AND tail both from the fp16 mirrors (working set 120 MB, L3-hot).
// hr = fp16(head)*rel_f32 built at run-switches; tail streams 4KB/edge.
// Edges with pre-clip score inside (-1.5, 2.5) (~70 sigma of the two-sided
// fp16 quantization error, std ~0.02) are queued for exact f32 refinement;
// all others saturate to 0/1 identically to the f32 reference.
__global__ __launch_bounds__(256) void score16(
    const float4* __restrict__ drug16, const float4* __restrict__ prot16,
    const float4* __restrict__ rddi,  const float4* __restrict__ rdpi,
    const int* __restrict__ sorted, const int* __restrict__ sd,
    int* __restrict__ refine, int* __restrict__ rcnt,
    float* __restrict__ out, int E)
{
    const int lane = threadIdx.x & 63;
    const int wpb = blockDim.x >> 6;
    const int wid = blockIdx.x * wpb + (threadIdx.x >> 6);
    const int nw = gridDim.x * wpb;
    const int cpr = (E + K_EDGES - 1) / K_EDGES;
    const int total_chunks = 3 * cpr;

    for (int c = wid; c < total_chunks; c += nw) {
        const int r = (c >= 2 * cpr) ? 2 : (c >= cpr) ? 1 : 0;
        const int ci = c - r * cpr;
        const int e_lo = ci * K_EDGES;
        const int n = min(K_EDGES, E - e_lo);

        const float4* xh = (r < 2) ? drug16 : prot16;   // head (fp16)
        const float4* xt = (r == 0) ? drug16 : prot16;  // tail (fp16)
        const float4* rel = (r == 0) ? rddi : rdpi;     // f32, L1-hot
        const int* sl  = sorted + (size_t)r * E + e_lo;
        const int* sdl = sd     + (size_t)r * E + e_lo;
        float* o = out + (size_t)r * E;

        int eL = 0, sdL = 0;               // chunk metadata in lanes, shfl out
        if (lane < n) { eL = sl[lane]; sdL = sdl[lane]; }

        float4 hr[8];
        int cur = -1;

        for (int i = 0; i < n; ++i) {
            const int sdi = __shfl(sdL, i);   // convergent: whole wave
            const int e   = __shfl(eL, i);    // convergent: whole wave
            const int s = sdi >> 16;
            if (s != cur) {                // wave-uniform branch
                cur = s;
                const float4* hp = xh + (size_t)s * T4;
#pragma unroll
                for (int g = 0; g < 4; ++g) {
                    float4 hv = hp[g * 64 + lane];
                    const __half2* h2 = (const __half2*)&hv;
                    float4 r0 = rel[2 * (g * 64 + lane)];
                    float4 r1 = rel[2 * (g * 64 + lane) + 1];
                    float2 f0 = __half22float2(h2[0]);
                    float2 f1 = __half22float2(h2[1]);
                    float2 f2 = __half22float2(h2[2]);
                    float2 f3 = __half22float2(h2[3]);
                    hr[2 * g].x     = f0.x * r0.x;
                    hr[2 * g].y     = f0.y * r0.y;
                    hr[2 * g].z     = f1.x * r0.z;
                    hr[2 * g].w     = f1.y * r0.w;
                    hr[2 * g + 1].x = f2.x * r1.x;
                    hr[2 * g + 1].y = f2.y * r1.y;
                    hr[2 * g + 1].z = f3.x * r1.z;
                    hr[2 * g + 1].w = f3.y * r1.w;
                }
            }
            const float4* tq = xt + (size_t)(sdi & 0xffff) * T4;
            float a0 = 0.f, a1 = 0.f, a2 = 0.f, a3 = 0.f;
#pragma unroll
            for (int g = 0; g < 4; ++g) {
                float4 tv = tq[g * 64 + lane];
                const __half2* t2 = (const __half2*)&tv;
                float2 f0 = __half22float2(t2[0]);
                float2 f1 = __half22float2(t2[1]);
                float2 f2 = __half22float2(t2[2]);
                float2 f3 = __half22float2(t2[3]);
                a0 = fmaf(hr[2 * g].x, f0.x, a0);
                a1 = fmaf(hr[2 * g].y, f0.y, a1);
                a2 = fmaf(hr[2 * g].z, f1.x, a2);
                a3 = fmaf(hr[2 * g].w, f1.y, a3);
                a0 = fmaf(hr[2 * g + 1].x, f2.x, a0);
                a1 = fmaf(hr[2 * g + 1].y, f2.y, a1);
                a2 = fmaf(hr[2 * g + 1].z, f3.x, a2);
                a3 = fmaf(hr[2 * g + 1].w, f3.y, a3);
            }
            float acc = (a0 + a1) + (a2 + a3);
#pragma unroll
            for (int off = 32; off; off >>= 1) acc += __shfl_down(acc, off, 64);
            if (lane == 0) {
                o[e] = fminf(fmaxf(acc, 0.f), 1.f);
                if (acc > -1.5f && acc < 2.5f) {
                    int p = atomicAdd(rcnt, 1);
                    refine[p] = (r << 20) | e;   // e < 2^17, r < 4
                }
            }
        }
    }
}

// ================= f32 refinement of borderline edges =====================
__global__ __launch_bounds__(256) void refine_f32(
    const float4* __restrict__ xdrug, const float4* __restrict__ xprot,
    const float4* __restrict__ rddi,  const float4* __restrict__ rdpi,
    const int* __restrict__ ddi_src, const int* __restrict__ ddi_dst,
    const int* __restrict__ dpi_src, const int* __restrict__ dpi_dst,
    const int* __restrict__ ppi_src, const int* __restrict__ ppi_dst,
    const int* __restrict__ refine, const int* __restrict__ rcnt,
    float* __restrict__ out, int E)
{
    const int lane = threadIdx.x & 63;
    const int wpb = blockDim.x >> 6;
    const int wid = blockIdx.x * wpb + (threadIdx.x >> 6);
    const int nw = gridDim.x * wpb;
    const int count = rcnt[0];
    for (int k = wid; k < count; k += nw) {
        const int pe = refine[k];
        const int r = pe >> 20, e = pe & 0xFFFFF;
        const float4 *hp, *tp, *rel;
        if (r == 0)      { hp = xdrug + (size_t)ddi_src[e] * D4; tp = xdrug + (size_t)ddi_dst[e] * D4; rel = rddi; }
        else if (r == 1) { hp = xdrug + (size_t)dpi_src[e] * D4; tp = xprot + (size_t)dpi_dst[e] * D4; rel = rdpi; }
        else             { hp = xprot + (size_t)ppi_src[e] * D4; tp = xprot + (size_t)ppi_dst[e] * D4; rel = rdpi; }
        float a0 = 0.f, a1 = 0.f, a2 = 0.f, a3 = 0.f;
#pragma unroll
        for (int j = 0; j < 8; ++j) {
            const int idx = j * 64 + lane;
            float4 h = hp[idx], t = tp[idx], rv = rel[idx];
            a0 = fmaf(h.x * rv.x, t.x, a0);
            a1 = fmaf(h.y * rv.y, t.y, a1);
            a2 = fmaf(h.z * rv.z, t.z, a2);
            a3 = fmaf(h.w * rv.w, t.w, a3);
        }
        float acc = (a0 + a1) + (a2 + a3);
#pragma unroll
        for (int off = 32; off; off >>= 1) acc += __shfl_down(acc, off, 64);
        if (lane == 0) out[(size_t)r * E + e] = fminf(fmaxf(acc, 0.f), 1.f);
    }
}

// ================= mid-tier: f32 sorted path ==============================
__global__ __launch_bounds__(256) void score_f32(
    const float4* __restrict__ xdrug, const float4* __restrict__ xprot,
    const float4* __restrict__ rddi,  const float4* __restrict__ rdpi,
    const int* __restrict__ sorted, const int* __restrict__ sd,
    float* __restrict__ out, int E)
{
    const int lane = threadIdx.x & 63;
    const int wpb = blockDim.x >> 6;
    const int wid = blockIdx.x * wpb + (threadIdx.x >> 6);
    const int nw = gridDim.x * wpb;
    const int cpr = (E + K_EDGES - 1) / K_EDGES;
    const int total_chunks = 3 * cpr;

    for (int c = wid; c < total_chunks; c += nw) {
        const int r = (c >= 2 * cpr) ? 2 : (c >= cpr) ? 1 : 0;
        const int ci = c - r * cpr;
        const int e_lo = ci * K_EDGES;
        const int n = min(K_EDGES, E - e_lo);

        const float4 *xs, *xd, *rel;
        if (r == 0)      { xs = xdrug; xd = xdrug; rel = rddi; }
        else if (r == 1) { xs = xdrug; xd = xprot; rel = rdpi; }
        else             { xs = xprot; xd = xprot; rel = rdpi; }
        const int* sl  = sorted + (size_t)r * E + e_lo;
        const int* sdl = sd     + (size_t)r * E + e_lo;
        float* o = out + (size_t)r * E;

        float4 hr[8];
        int cur = -1;
        for (int i = 0; i < n; ++i) {
            const int e = sl[i];
            const int sdi = sdl[i];
            const int s = sdi >> 16;
            if (s != cur) {
                cur = s;
                const float4* hp = xs + (size_t)s * D4;
#pragma unroll
                for (int j = 0; j < 8; ++j) {
                    float4 h = hp[j * 64 + lane], rv = rel[j * 64 + lane];
                    hr[j].x = h.x * rv.x; hr[j].y = h.y * rv.y;
                    hr[j].z = h.z * rv.z; hr[j].w = h.w * rv.w;
                }
            }
            const float4* tp = xd + (size_t)(sdi & 0xffff) * D4;
            float acc = 0.f;
#pragma unroll
            for (int j = 0; j < 8; ++j) {
                float4 t = tp[j * 64 + lane];
                acc = fmaf(hr[j].x, t.x, acc);
                acc = fmaf(hr[j].y, t.y, acc);
                acc = fmaf(hr[j].z, t.z, acc);
                acc = fmaf(hr[j].w, t.w, acc);
            }
#pragma unroll
            for (int off = 32; off; off >>= 1) acc += __shfl_down(acc, off, 64);
            if (lane == 0) o[e] = fminf(fmaxf(acc, 0.f), 1.f);
        }
    }
}

// ================= last-resort direct kernel ==============================
__global__ __launch_bounds__(256) void edge_score_all(
    const float4* __restrict__ xdrug, const float4* __restrict__ xprot,
    const float4* __restrict__ rddi,  const float4* __restrict__ rdpi,
    const int* __restrict__ ddi_src, const int* __restrict__ ddi_dst,
    const int* __restrict__ dpi_src, const int* __restrict__ dpi_dst,
    const int* __restrict__ ppi_src, const int* __restrict__ ppi_dst,
    float* __restrict__ out, int E)
{
    __shared__ float4 srel[2][D4];
    for (int i = threadIdx.x; i < D4; i += blockDim.x) {
        srel[0][i] = rddi[i];
        srel[1][i] = rdpi[i];
    }
    __syncthreads();
    const int lane = threadIdx.x & 63;
    const int wpb = blockDim.x >> 6;
    int wid = blockIdx.x * wpb + (threadIdx.x >> 6);
    const int nw = gridDim.x * wpb;
    const int total = 3 * E;
    for (int e = wid; e < total; e += nw) {
        const float4 *hp, *tp;
        int sel;
        if (e < E)          { hp = xdrug + (size_t)ddi_src[e] * D4; tp = xdrug + (size_t)ddi_dst[e] * D4; sel = 0; }
        else if (e < 2 * E) { int k = e - E;     hp = xdrug + (size_t)dpi_src[k] * D4; tp = xprot + (size_t)dpi_dst[k] * D4; sel = 1; }
        else                { int k = e - 2 * E; hp = xprot + (size_t)ppi_src[k] * D4; tp = xprot + (size_t)ppi_dst[k] * D4; sel = 1; }
        float acc = 0.f;
#pragma unroll
        for (int j = 0; j < 8; ++j) {
            const int idx = j * 64 + lane;
            float4 h = hp[idx], t = tp[idx], rr = srel[sel][idx];
            acc = fmaf(h.x * rr.x, t.x, acc);
            acc = fmaf(h.y * rr.y, t.y, acc);
            acc = fmaf(h.z * rr.z, t.z, acc);
            acc = fmaf(h.w * rr.w, t.w, acc);
        }
#pragma unroll
        for (int off = 32; off; off >>= 1) acc += __shfl_down(acc, off, 64);
        if (lane == 0) out[e] = fminf(fmaxf(acc, 0.f), 1.f);
    }
}

extern "C" void kernel_launch(void* const* d_in, const int* in_sizes, int n_in,
                              void* d_out, int out_size, void* d_ws, size_t ws_size,
                              hipStream_t stream) {
    const float* x_drug    = (const float*)d_in[0];
    const float* x_protein = (const float*)d_in[1];
    const float* rel_ddi   = (const float*)d_in[2];
    const float* rel_dpi   = (const float*)d_in[3];
    const int* ddi_src = (const int*)d_in[4];
    const int* ddi_dst = (const int*)d_in[5];
    const int* dpi_src = (const int*)d_in[6];
    const int* dpi_dst = (const int*)d_in[7];
    const int* ppi_src = (const int*)d_in[8];
    const int* ppi_dst = (const int*)d_in[9];

    const int D  = in_sizes[2];              // 2048
    const int nd = in_sizes[0] / D;          // N_DRUG
    const int np = in_sizes[1] / D;          // N_PROT
    const int E  = in_sizes[4];              // edges per relation
    float* out = (float*)d_out;

    const int ndp = ((nd + 63) / 64) * 64;   // 64-aligned
    const int npp = ((np + 63) / 64) * 64;
    const int CB  = 2 * ndp + npp;           // buckets: (rel, src)

    const size_t b_d16 = (size_t)nd * D * 2; // fp16 mirror sizes (16B-aligned)
    const size_t b_p16 = (size_t)np * D * 2;
    const size_t ints_sort = (size_t)(2 * CB + 16 + 6 * E) * sizeof(int);
    const size_t need_sort = ints_sort;
    const size_t need_full = b_d16 + b_p16 + ints_sort + (size_t)3 * E * sizeof(int);

    if (ws_size < need_sort) {               // last resort: direct kernel
        edge_score_all<<<2048, 256, 0, stream>>>(
            (const float4*)x_drug, (const float4*)x_protein,
            (const float4*)rel_ddi, (const float4*)rel_dpi,
            ddi_src, ddi_dst, dpi_src, dpi_dst, ppi_src, ppi_dst, out, E);
        return;
    }

    const bool full = (ws_size >= need_full);
    char* wp = (char*)d_ws;
    __half* drug16 = nullptr; __half* prot16 = nullptr;
    if (full) {
        drug16 = (__half*)wp;  wp += b_d16;  // 16B-aligned (D*2 = 4096B rows)
        prot16 = (__half*)wp;  wp += b_p16;
    }
    int* cnt    = (int*)wp;                  // CB
    int* aux    = cnt + CB;                  // 16: cursors[0..2], rcnt at [8]
    int* base   = aux + 16;                  // CB
    int* sorted = base + CB;                 // 3E (edge ids, src-grouped)
    int* sd     = sorted + 3 * E;            // 3E ((src<<16)|dst)
    int* refine = sd + 3 * E;                // 3E worst case (full path only)

    if (full)
        cvt16<<<2048, 256, 0, stream>>>(
            (const float4*)x_drug, (const float4*)x_protein,
            drug16, prot16, nd * (D / 4), np * (D / 4));

    zero_ints<<<(CB + 16 + 255) / 256, 256, 0, stream>>>(cnt, CB + 16);
    hist3<<<1024, 256, 0, stream>>>(ddi_src, dpi_src, ppi_src, E, cnt, ndp);
    alloc3<<<(CB + 255) / 256, 256, 0, stream>>>(cnt, base, aux, ndp, CB);
    scatter3<<<1024, 256, 0, stream>>>(ddi_src, ddi_dst, dpi_src, dpi_dst,
                                       ppi_src, ppi_dst, E, base, ndp, sorted, sd);

    if (full) {
        score16<<<2048, 256, 0, stream>>>(
            (const float4*)drug16, (const float4*)prot16,
            (const float4*)rel_ddi, (const float4*)rel_dpi,
            sorted, sd, refine, aux + 8, out, E);
        refine_f32<<<1024, 256, 0, stream>>>(
            (const float4*)x_drug, (const float4*)x_protein,
            (const float4*)rel_ddi, (const float4*)rel_dpi,
            ddi_src, ddi_dst, dpi_src, dpi_dst, ppi_src, ppi_dst,
            refine, aux + 8, out, E);
    } else {
        score_f32<<<2048, 256, 0, stream>>>(
            (const float4*)x_drug, (const float4*)x_protein,
            (const float4*)rel_ddi, (const float4*)rel_dpi,
            sorted, sd, out, E);
    }
}